// Round 3
// baseline (135.118 us; speedup 1.0000x reference)
//
#include <hip/hip_runtime.h>

// LocalAutoCorr2D: out[b,iy,ix,c,dy,dx] =
//   sum_{u,v in [0,8)} x[b,c,4iy+u,4ix+v] * x[b,c,4iy+dy+u-4,4ix+dx+v-4]  (zero-padded)
//
// B=4 C=128 H=W=128, kh=kw=8, sh=sw=4, nh=nw=31.
// Block: 256 threads = 16 channels x (4x x 4y) positions. 48.4KB LDS -> 3 blocks/CU.
// Per-thread: 8x8 output register tile; coalesced stores via LDS transpose.

#define Bn 4
#define Cn 128
#define Hn 128
#define Wn 128
#define NH 31
#define NW 31
#define CB 16          // channels per block
#define PXT 4          // x positions per block
#define PYT 4          // y positions per block
#define TROWS 27       // (PYT-1)*4 + 15
#define RST 28         // row stride in floats (27 used)
#define CST (TROWS*RST)  // 756 floats/channel
#define F4C (TROWS*7)    // 189 float4 staged per channel
#define PST 273          // transpose: float4 stride per position (1092 words % 32 = 4)

__global__ __launch_bounds__(256, 3)
void lac_kernel(const float* __restrict__ x, float* __restrict__ out) {
    __shared__ float sm[CB * CST];   // 48,384 B -> 3 blocks/CU

    const int bid = blockIdx.x;
    const int ct = bid & 7;          // channel tile 0..7
    const int tx = (bid >> 3) & 7;   // x tile 0..7
    const int ty = (bid >> 6) & 7;   // y tile 0..7
    const int b  = bid >> 9;         // batch 0..3
    const int c0 = ct * CB;
    const int gy0 = ty * (PYT * 4) - 4;   // first staged global row
    const int gx0 = tx * (PXT * 4) - 4;   // first staged global col
    const int tid = threadIdx.x;

    // ---- stage region: CB channels x TROWS rows x 28 cols (float4 chunks, LDS-linear) ----
    for (int i = tid; i < CB * F4C; i += 256) {
        const int c   = i / F4C;
        const int rem = i - c * F4C;
        const int r   = rem / 7;
        const int q   = rem - r * 7;
        const int y   = gy0 + r;
        const int xc  = gx0 + q * 4;
        const float* src = x + (((size_t)(b * Cn + c0 + c) * Hn + y) * Wn + xc);
        float4 v;
        if (y >= 0 && y < Hn && xc >= 0 && xc + 3 < Wn) {
            v = *reinterpret_cast<const float4*>(src);
        } else if (y >= 0 && y < Hn) {
            v.x = (xc + 0 >= 0 && xc + 0 < Wn) ? src[0] : 0.0f;
            v.y = (xc + 1 >= 0 && xc + 1 < Wn) ? src[1] : 0.0f;
            v.z = (xc + 2 >= 0 && xc + 2 < Wn) ? src[2] : 0.0f;
            v.w = (xc + 3 >= 0 && xc + 3 < Wn) ? src[3] : 0.0f;
        } else {
            v = make_float4(0.0f, 0.0f, 0.0f, 0.0f);
        }
        reinterpret_cast<float4*>(sm)[i] = v;   // linear: i == c*189 + r*7 + q
    }
    __syncthreads();

    // ---- compute: thread = (channel cs, position px,py), 64 outputs in regs ----
    const int cs  = tid & 15;
    const int pos = tid >> 4;        // 0..15
    const int px  = pos & 3;
    const int py  = pos >> 2;
    const float* rg = &sm[cs * CST + (py * 4) * RST + px * 4];

    // base 8x8 window = region rows u+4, cols 4..11
    float bs[8][8];
#pragma unroll
    for (int u = 0; u < 8; ++u) {
        float4 t0 = *reinterpret_cast<const float4*>(&rg[(u + 4) * RST + 4]);
        float4 t1 = *reinterpret_cast<const float4*>(&rg[(u + 4) * RST + 8]);
        bs[u][0] = t0.x; bs[u][1] = t0.y; bs[u][2] = t0.z; bs[u][3] = t0.w;
        bs[u][4] = t1.x; bs[u][5] = t1.y; bs[u][6] = t1.z; bs[u][7] = t1.w;
    }

    float acc[8][8];
#pragma unroll
    for (int i = 0; i < 8; ++i)
#pragma unroll
        for (int j = 0; j < 8; ++j) acc[i][j] = 0.0f;

#pragma unroll
    for (int r = 0; r < 15; ++r) {
        float rw[16];
        float4 q0 = *reinterpret_cast<const float4*>(&rg[r * RST + 0]);
        float4 q1 = *reinterpret_cast<const float4*>(&rg[r * RST + 4]);
        float4 q2 = *reinterpret_cast<const float4*>(&rg[r * RST + 8]);
        float4 q3 = *reinterpret_cast<const float4*>(&rg[r * RST + 12]);
        rw[0]  = q0.x; rw[1]  = q0.y; rw[2]  = q0.z; rw[3]  = q0.w;
        rw[4]  = q1.x; rw[5]  = q1.y; rw[6]  = q1.z; rw[7]  = q1.w;
        rw[8]  = q2.x; rw[9]  = q2.y; rw[10] = q2.z; rw[11] = q2.w;
        rw[12] = q3.x; rw[13] = q3.y; rw[14] = q3.z; rw[15] = q3.w;
#pragma unroll
        for (int u = 0; u < 8; ++u) {
            const int dy = r - u;           // compile-time after unroll
            if (dy >= 0 && dy < 8) {
#pragma unroll
                for (int v = 0; v < 8; ++v) {
                    const float bv = bs[u][v];
#pragma unroll
                    for (int dx = 0; dx < 8; ++dx)
                        acc[dy][dx] = fmaf(bv, rw[v + dx], acc[dy][dx]);
                }
            }
        }
    }

    // ---- coalesced store via LDS transpose, 2 rounds of 8 positions ----
    // transpose layout (float4 units): [p(8) stride PST][c(16) stride 17][dy*2+q(16)]
    float4* lds4 = reinterpret_cast<float4*>(sm);
#pragma unroll
    for (int rnd = 0; rnd < 2; ++rnd) {
        __syncthreads();
        if ((pos >> 3) == rnd) {
            const int p = pos & 7;
#pragma unroll
            for (int dy = 0; dy < 8; ++dy) {
                lds4[p * PST + cs * 17 + dy * 2 + 0] =
                    make_float4(acc[dy][0], acc[dy][1], acc[dy][2], acc[dy][3]);
                lds4[p * PST + cs * 17 + dy * 2 + 1] =
                    make_float4(acc[dy][4], acc[dy][5], acc[dy][6], acc[dy][7]);
            }
        }
        __syncthreads();
        // each position owns a contiguous 256-float4 output chunk; 256 threads
        // store exactly one float4 each -> fully coalesced 4KB burst.
#pragma unroll
        for (int p = 0; p < 8; ++p) {
            const int pp  = rnd * 8 + p;
            const int ppx = pp & 3;
            const int ppy = pp >> 2;
            const int iy  = ty * PYT + ppy;
            const int ix  = tx * PXT + ppx;
            if (iy < NH && ix < NW) {
                float4* obase = reinterpret_cast<float4*>(
                    out + ((((size_t)b * NH + iy) * NW + ix) * Cn + c0) * 64);
                const int c   = tid >> 4;   // 0..15
                const int rem = tid & 15;   // 0..15
                obase[tid] = lds4[p * PST + c * 17 + rem];
            }
        }
    }
}

extern "C" void kernel_launch(void* const* d_in, const int* in_sizes, int n_in,
                              void* d_out, int out_size, void* d_ws, size_t ws_size,
                              hipStream_t stream) {
    const float* x = (const float*)d_in[0];
    float* out = (float*)d_out;
    // grid = B(4) * ty(8) * tx(8) * ct(8) = 2048 blocks
    lac_kernel<<<dim3(2048), dim3(256), 0, stream>>>(x, out);
}

// Round 4
// 94.347 us; speedup vs baseline: 1.4321x; 1.4321x over previous
//
#include <hip/hip_runtime.h>

// LocalAutoCorr2D: out[b,iy,ix,c,dy,dx] =
//   sum_{u,v in [0,8)} x[b,c,4iy+u,4ix+v] * x[b,c,4iy+dy+u-4,4ix+dx+v-4]  (zero-padded)
//
// B=4 C=128 H=W=128, kh=kw=8, sh=sw=4, nh=nw=31.
// Block: 256 threads = 16 channels x (4x x 4y) positions. 48.4KB LDS -> 3 blocks/CU.
// Per-thread: 8x8 output register tile. Base-window rows are STREAMED from LDS
// (not register-cached) to keep the live set ~100 VGPRs -> no scratch spills.

#define Bn 4
#define Cn 128
#define Hn 128
#define Wn 128
#define NH 31
#define NW 31
#define CB 16          // channels per block
#define PXT 4          // x positions per block
#define PYT 4          // y positions per block
#define TROWS 27       // (PYT-1)*4 + 15
#define RST 28         // row stride in floats (27 used)
#define CST (TROWS*RST)  // 756 floats/channel
#define F4C (TROWS*7)    // 189 float4 staged per channel
#define PST 273          // transpose: float4 stride per position (1092 words % 32 = 4)

__global__ __launch_bounds__(256, 3)
void lac_kernel(const float* __restrict__ x, float* __restrict__ out) {
    __shared__ float sm[CB * CST];   // 48,384 B -> 3 blocks/CU

    const int bid = blockIdx.x;
    const int ct = bid & 7;          // channel tile 0..7
    const int tx = (bid >> 3) & 7;   // x tile 0..7
    const int ty = (bid >> 6) & 7;   // y tile 0..7
    const int b  = bid >> 9;         // batch 0..3
    const int c0 = ct * CB;
    const int gy0 = ty * (PYT * 4) - 4;   // first staged global row
    const int gx0 = tx * (PXT * 4) - 4;   // first staged global col
    const int tid = threadIdx.x;

    // ---- stage region: CB channels x TROWS rows x 28 cols (float4 chunks, LDS-linear) ----
    for (int i = tid; i < CB * F4C; i += 256) {
        const int c   = i / F4C;
        const int rem = i - c * F4C;
        const int r   = rem / 7;
        const int q   = rem - r * 7;
        const int y   = gy0 + r;
        const int xc  = gx0 + q * 4;
        const float* src = x + (((size_t)(b * Cn + c0 + c) * Hn + y) * Wn + xc);
        float4 v;
        if (y >= 0 && y < Hn && xc >= 0 && xc + 3 < Wn) {
            v = *reinterpret_cast<const float4*>(src);
        } else if (y >= 0 && y < Hn) {
            v.x = (xc + 0 >= 0 && xc + 0 < Wn) ? src[0] : 0.0f;
            v.y = (xc + 1 >= 0 && xc + 1 < Wn) ? src[1] : 0.0f;
            v.z = (xc + 2 >= 0 && xc + 2 < Wn) ? src[2] : 0.0f;
            v.w = (xc + 3 >= 0 && xc + 3 < Wn) ? src[3] : 0.0f;
        } else {
            v = make_float4(0.0f, 0.0f, 0.0f, 0.0f);
        }
        reinterpret_cast<float4*>(sm)[i] = v;   // linear: i == c*189 + r*7 + q
    }
    __syncthreads();

    // ---- compute: thread = (channel cs, position px,py), 64 outputs in regs ----
    const int cs  = tid & 15;
    const int pos = tid >> 4;        // 0..15
    const int px  = pos & 3;
    const int py  = pos >> 2;
    const float* rg = &sm[cs * CST + (py * 4) * RST + px * 4];

    float acc[8][8];
#pragma unroll
    for (int i = 0; i < 8; ++i)
#pragma unroll
        for (int j = 0; j < 8; ++j) acc[i][j] = 0.0f;

#pragma unroll
    for (int r = 0; r < 15; ++r) {
        float rw[16];
        float4 q0 = *reinterpret_cast<const float4*>(&rg[r * RST + 0]);
        float4 q1 = *reinterpret_cast<const float4*>(&rg[r * RST + 4]);
        float4 q2 = *reinterpret_cast<const float4*>(&rg[r * RST + 8]);
        float4 q3 = *reinterpret_cast<const float4*>(&rg[r * RST + 12]);
        rw[0]  = q0.x; rw[1]  = q0.y; rw[2]  = q0.z; rw[3]  = q0.w;
        rw[4]  = q1.x; rw[5]  = q1.y; rw[6]  = q1.z; rw[7]  = q1.w;
        rw[8]  = q2.x; rw[9]  = q2.y; rw[10] = q2.z; rw[11] = q2.w;
        rw[12] = q3.x; rw[13] = q3.y; rw[14] = q3.z; rw[15] = q3.w;
#pragma unroll
        for (int u = 0; u < 8; ++u) {
            const int dy = r - u;           // compile-time after unroll
            if (dy >= 0 && dy < 8) {
                // stream base row u from LDS (region row u+4, cols 4..11; 16B-aligned)
                float4 b0 = *reinterpret_cast<const float4*>(&rg[(u + 4) * RST + 4]);
                float4 b1 = *reinterpret_cast<const float4*>(&rg[(u + 4) * RST + 8]);
                float bsr[8];
                bsr[0] = b0.x; bsr[1] = b0.y; bsr[2] = b0.z; bsr[3] = b0.w;
                bsr[4] = b1.x; bsr[5] = b1.y; bsr[6] = b1.z; bsr[7] = b1.w;
#pragma unroll
                for (int v = 0; v < 8; ++v) {
                    const float bv = bsr[v];
#pragma unroll
                    for (int dx = 0; dx < 8; ++dx)
                        acc[dy][dx] = fmaf(bv, rw[v + dx], acc[dy][dx]);
                }
            }
        }
    }

    // ---- coalesced store via LDS transpose, 2 rounds of 8 positions ----
    // transpose layout (float4 units): [p(8) stride PST][c(16) stride 17][dy*2+q(16)]
    float4* lds4 = reinterpret_cast<float4*>(sm);
#pragma unroll
    for (int rnd = 0; rnd < 2; ++rnd) {
        __syncthreads();
        if ((pos >> 3) == rnd) {
            const int p = pos & 7;
#pragma unroll
            for (int dy = 0; dy < 8; ++dy) {
                lds4[p * PST + cs * 17 + dy * 2 + 0] =
                    make_float4(acc[dy][0], acc[dy][1], acc[dy][2], acc[dy][3]);
                lds4[p * PST + cs * 17 + dy * 2 + 1] =
                    make_float4(acc[dy][4], acc[dy][5], acc[dy][6], acc[dy][7]);
            }
        }
        __syncthreads();
        // each position owns a contiguous 256-float4 output chunk; 256 threads
        // store exactly one float4 each -> fully coalesced 4KB burst.
#pragma unroll
        for (int p = 0; p < 8; ++p) {
            const int pp  = rnd * 8 + p;
            const int ppx = pp & 3;
            const int ppy = pp >> 2;
            const int iy  = ty * PYT + ppy;
            const int ix  = tx * PXT + ppx;
            if (iy < NH && ix < NW) {
                float4* obase = reinterpret_cast<float4*>(
                    out + ((((size_t)b * NH + iy) * NW + ix) * Cn + c0) * 64);
                const int c   = tid >> 4;   // 0..15
                const int rem = tid & 15;   // 0..15
                obase[tid] = lds4[p * PST + c * 17 + rem];
            }
        }
    }
}

extern "C" void kernel_launch(void* const* d_in, const int* in_sizes, int n_in,
                              void* d_out, int out_size, void* d_ws, size_t ws_size,
                              hipStream_t stream) {
    const float* x = (const float*)d_in[0];
    float* out = (float*)d_out;
    // grid = B(4) * ty(8) * tx(8) * ct(8) = 2048 blocks
    lac_kernel<<<dim3(2048), dim3(256), 0, stream>>>(x, out);
}